// Round 13
// baseline (27.860 us; speedup 1.0000x reference)
//
#include <hip/hip_runtime.h>
#include <cstdint>

// Rule 30, 2 states, r=1, wrap. idx = L + 2C + 4R, table = bits of 30
// reduces to: new = R ^ (C | L).
//
// B=16 rows, W=2048 cells, T=1024 steps, history = T+1 states.
// Output: int32 [B][T+1][W] (reference returns uint8 -> harness int32).
//
// Round-13 = round-11 STAGGER structure + round-12 PLAIN stores.
//   R12 (R8 + plain stores): 27.4us — plain beats NT (29.4) at identical
//   structure; NT's ~4.6 TB/s path was the R8-R11 plateau and masked R11's
//   stagger benefit. R12's residual over the ~20.5us per-CU write floor
//   (~6.9us) matches R8's longest-head chain (1024 steps ~4.5us) + ramp.
//   This round staggers chunk seeds so max head = 240 steps (~1.1us) and
//   mid-chains hide under store phases — now with the faster plain-store
//   path. Compose of two verified wins; single remaining variable.
//
//   Grid = 256 blocks = 16 rows x 16 stagger slots; block (b,j) emits the
//   16-state chunks seeded at steps j*16 + k*256 (k=0..3), double-buffered
//   in LDS. Chain (wave 0 only): ghost-zone window, one 32-bit shuffle
//   pair per 16 steps; rule on the 64-bit window is
//   win = (win>>1) ^ (win | (win<<1)); middle 32 bits valid 16 steps.

#define B 16
#define W 2048
#define T_ITERS 1024
#define HIST (T_ITERS + 1)
#define LANES 64
#define CH 16                      // states per chunk (= halo validity)
#define NCH 4                      // chunks per block
#define JSLOTS 16                  // stagger slots per row
#define SPACING (JSLOTS * CH)      // 256 steps between a block's chunks
#define ROW_I4 (W / 4)             // 512 int4 per state row

typedef unsigned long long u64;
typedef int v4i __attribute__((ext_vector_type(4)));

__device__ __forceinline__ void store_nib(v4i* o, unsigned nib) {
    v4i f;
    f.x = (int)(nib & 1u);
    f.y = (int)((nib >> 1) & 1u);
    f.z = (int)((nib >> 2) & 1u);
    f.w = (int)((nib >> 3) & 1u);
    *o = f;                              // plain global_store_dwordx4
}

// one 16-step exchange group; if dst != nullptr, record the 16 states
__device__ __forceinline__ unsigned chain16(unsigned m, int l, unsigned* dst) {
    unsigned left  = __shfl(m, (l + LANES - 1) & (LANES - 1));
    unsigned right = __shfl(m, (l + 1) & (LANES - 1));
    // window bit p = cell (32l - 16 + p); bits [16..47] = own cells
    u64 win = ((u64)(left >> 16)) | ((u64)m << 16) | ((u64)right << 48);
    if (dst) {
        #pragma unroll
        for (int j = 0; j < CH; ++j) {
            win = (win >> 1) ^ (win | (win << 1));   // rule 30, 64 bits
            m = (unsigned)(win >> 16);               // valid for j<=15
            dst[j * LANES] = m;                      // 2 lanes/bank: free
        }
    } else {
        #pragma unroll
        for (int j = 0; j < CH; ++j)
            win = (win >> 1) ^ (win | (win << 1));
        m = (unsigned)(win >> 16);
    }
    return m;
}

__global__ __launch_bounds__(256) void ca_stagger(const float* __restrict__ x,
                                                  v4i* __restrict__ out) {
    __shared__ unsigned st[2][CH][LANES];    // double-buffered chunk
    __shared__ unsigned st0[LANES];          // packed t=0 (j==0 only)

    const int blk = blockIdx.x;
    const int b = blk & (B - 1);             // row
    const int j = blk >> 4;                  // stagger slot 0..15
    const int tid = threadIdx.x;
    const int wave = tid >> 6;               // 0..3
    const int l = tid & 63;                  // lane

    unsigned m = 0;
    if (wave == 0) {
        // ---- pack 32 thresholded floats into u32 (bit i = cell 32l+i) ----
        const float4* xv = (const float4*)(x + (size_t)b * W + (size_t)l * 32);
        #pragma unroll
        for (int i = 0; i < 8; ++i) {
            float4 v = xv[i];
            unsigned n = (v.x >= 0.5f ? 1u : 0u) | (v.y >= 0.5f ? 2u : 0u) |
                         (v.z >= 0.5f ? 4u : 0u) | (v.w >= 0.5f ? 8u : 0u);
            m |= n << (4 * i);
        }
        if (j == 0) st0[l] = m;

        // ---- head: j groups of 16 steps (<= 240 steps ~ 1.1us) ----
        for (int g = 0; g < j; ++g) m = chain16(m, l, nullptr);
        // ---- emit chunk 0 (seed step j*16) into buffer 0 ----
        m = chain16(m, l, &st[0][0][l]);
    }
    __syncthreads();

    // ---- t=0 row (j==0 blocks): 512 int4 across 256 threads ----
    if (j == 0) {
        v4i* o = out + ((size_t)b * HIST) * ROW_I4;
        #pragma unroll
        for (int h = 0; h < 2; ++h) {
            int c = tid + 256 * h;
            unsigned u = st0[c >> 3];
            store_nib(o + c, (u >> ((c & 7) * 4)) & 0xFu);
        }
    }

    // ---- chunks: wave 0 chains 240 steps + emits k+1 || all store k ----
    for (int k = 0; k < NCH; ++k) {
        if (wave == 0 && k < NCH - 1) {
            // from state (seed_k + 16) to seed_{k+1}: 15 groups, no store
            for (int g = 0; g < JSLOTS - 1; ++g) m = chain16(m, l, nullptr);
            m = chain16(m, l, &st[(k + 1) & 1][0][l]);   // emit chunk k+1
        }
        // store chunk k: 16 states, 4 per wave; plain int4 wave-stores.
        // nibble c of a packed row: word c>>3 = (l>>3)+8i, shift (l&7)*4.
        const size_t t0 = (size_t)(j * CH + k * SPACING + 1);
        #pragma unroll
        for (int jj = 0; jj < 4; ++jj) {
            const int jr = wave * 4 + jj;
            v4i* o = out + ((size_t)b * HIST + t0 + jr) * ROW_I4;
            #pragma unroll
            for (int i = 0; i < 8; ++i) {
                unsigned u = st[k & 1][jr][(l >> 3) + 8 * i];
                store_nib(o + l + 64 * i, (u >> ((l & 7) * 4)) & 0xFu);
            }
        }
        __syncthreads();   // st[k&1] fully read before overwrite at k+2;
                           // st[(k+1)&1] fully written before reads at k+1
    }
}

extern "C" void kernel_launch(void* const* d_in, const int* in_sizes, int n_in,
                              void* d_out, int out_size, void* d_ws, size_t ws_size,
                              hipStream_t stream) {
    const float* x = (const float*)d_in[0];
    // 256 independent blocks (1 per CU, 4 waves each); no workspace needed.
    ca_stagger<<<B * JSLOTS, 256, 0, stream>>>(x, (v4i*)d_out);
}